// Round 7
// baseline (524.673 us; speedup 1.0000x reference)
//
#include <hip/hip_runtime.h>
#include <stdint.h>

typedef unsigned short u16;
typedef __bf16 bf8 __attribute__((ext_vector_type(8)));
typedef float f32x4 __attribute__((ext_vector_type(4)));

#define SEQ 2048
#define HIDDEN 4096
#define DQKV 6144   // 48 heads * 128
#define HD 128

// async global->LDS, 16B/lane. LDS dest is wave-uniform base + lane*16 (m104/m108);
// all staging layouts below are laid out so lane l's element lands at base + l*16B.
#define GLOAD_LDS16(g, l)                                                            \
    __builtin_amdgcn_global_load_lds((const __attribute__((address_space(1))) void*)(g), \
                                     (__attribute__((address_space(3))) void*)(l), 16, 0, 0)

__device__ __forceinline__ u16 f2bf(float f) {
    union { float f; unsigned u; } v{f};
    unsigned r = (v.u + 0x7fff + ((v.u >> 16) & 1)) >> 16;
    return (u16)r;
}
__device__ __forceinline__ float bf2f(u16 b) {
    union { unsigned u; float f; } v;
    v.u = ((unsigned)b) << 16;
    return v.f;
}

// ---------------- pre-pass kernels ----------------

__global__ void convert_bf16_kernel(const float* __restrict__ in, u16* __restrict__ out) {
    int i = (blockIdx.x * 256 + threadIdx.x) * 4;
    float4 v = *(const float4*)(in + i);
    u16 o[4] = {f2bf(v.x), f2bf(v.y), f2bf(v.z), f2bf(v.w)};
    *(uint2*)(out + i) = *(uint2*)o;
}

// in fp32 [K][N] -> out bf16 [N][K]
__global__ void transpose_w_kernel(const float* __restrict__ in, u16* __restrict__ out, int K, int N) {
    __shared__ u16 tile[64][65];
    int tn = N >> 6;
    int bk = blockIdx.x / tn, bn = blockIdx.x % tn;
    int k0 = bk * 64, n0 = bn * 64;
    int c = threadIdx.x & 63, r0 = threadIdx.x >> 6;
#pragma unroll
    for (int r = r0; r < 64; r += 4)
        tile[r][c] = f2bf(in[(size_t)(k0 + r) * N + n0 + c]);
    __syncthreads();
#pragma unroll
    for (int r = r0; r < 64; r += 4)
        out[(size_t)(n0 + r) * K + k0 + c] = tile[c][r];
}

// RoPE in-place on Q/K heads (0..39) of xqkv [2048][6144]
__global__ void rope_kernel(u16* __restrict__ x) {
    const int row = blockIdx.x / 10, hg = blockIdx.x % 10;
    const int head = hg * 4 + (threadIdx.x >> 6), j = threadIdx.x & 63;
    u16* p = x + (size_t)row * DQKV + head * HD + j;
    float x1 = bf2f(p[0]), x2 = bf2f(p[64]);
    float inv = exp2f(-(float)j * 0.20762050593045952f); // log2(10000)/64
    float s, c;
    sincosf((float)row * inv, &s, &c);
    p[0] = f2bf(x1 * c - x2 * s);
    p[64] = f2bf(x1 * s + x2 * c);
}

// V heads (40..47) of xqkv [2048][6144] -> VT [8][128][2048]
__global__ void transpose_v_kernel(const u16* __restrict__ xqkv, u16* __restrict__ vt) {
    __shared__ u16 tile[64][65];
    int h = blockIdx.x >> 6;
    int t = blockIdx.x & 63;
    int s0 = (t >> 1) * 64, d0 = (t & 1) * 64;
    int c = threadIdx.x & 63, r0 = threadIdx.x >> 6;
    const u16* src = xqkv + (40 + h) * HD + d0;
#pragma unroll
    for (int r = r0; r < 64; r += 4)
        tile[r][c] = src[(size_t)(s0 + r) * DQKV + c];
    __syncthreads();
    u16* dst = vt + ((size_t)h * HD + d0) * SEQ + s0;
#pragma unroll
    for (int r = r0; r < 64; r += 4)
        dst[(size_t)r * SEQ + c] = tile[c][r];
}

// ---------------- GEMM: C[M][*] = A[M][4096] * BT[N][4096]^T ----------------
// Round-5 structure (best measured: 107.5 us, 0 bank conflicts, 958 TF) with
// one change: MODE0 wave split 2Mx4N -> 4Mx2N (WM=4, WN=6). Frag reads/wave/
// K-tile drop 22 -> 20 at identical MFMA count and identical (verified) LDS
// read pattern; A staging moves wholly to the K-tile boundary (A lines stay
// live through p3 for their owner wave under 4M split).
// MODE 0: 256x192 tile (8x32 grid), bf16 out stride 6144, waves 4Mx2N.
// MODE 1: 128x256 tile (16x16 grid), f32 out stride 4096, waves 2Mx4N.
// T1 XCD chunking kept (FETCH -10%, time-neutral). Swizzle (T2): logical
// (r,c16B) at phys c ^ (r&7) via pre-permuted gload source col (rule #21);
// zero conflicts measured. Counted vmcnt(NL), never 0 in steady state (T4):
// at boundary of tile t, outstanding = B(t+1),A(t+1),B(t+2),A(t+2); vmcnt(NL)
// drains exactly through A(t+1). setprio around MFMA clusters (T5).
template <int BM, int BN, int MODE>
__global__ __launch_bounds__(512, 2) void gemm8p_kernel(const u16* __restrict__ A,
                                                        const u16* __restrict__ BT,
                                                        u16* __restrict__ Cbf,
                                                        float* __restrict__ Cf) {
    constexpr int WAVES_N = (MODE == 0) ? 2 : 4;
    // 8 waves as (8/WAVES_N) x WAVES_N; wave owns BM*WAVES_N/8 rows
    constexpr int WM = BM * WAVES_N / 128;   // m-frags per wave (4, 4)
    constexpr int WN = BN / (WAVES_N * 16);  // n-frags per wave (6, 4)
    constexpr int MP = WM / 4;               // m-frags per phase (1)
    static_assert(WM >= 4 && MP >= 1, "wave split arithmetic");
    constexpr int NLA = BM / 64, NLB = BN / 64, NL = NLA + NLB;
    constexpr int NBN = ((MODE == 0) ? DQKV : HIDDEN) / BN;
    constexpr int NBM = SEQ / BM;
    constexpr int CSTR = (MODE == 0) ? DQKV : HIDDEN;
    constexpr int NT = 64;               // K / 64
    static_assert(NBM * NBN == 256, "grid must be exactly 256 blocks");
    __shared__ __align__(16) u16 lds[2][(BM + BN) * 64];

    const int tid = threadIdx.x;
    const int w = tid >> 6, l = tid & 63, l15 = l & 15, q4 = l >> 4;
    const int wm = w / WAVES_N, wn = w % WAVES_N;

    // T1: XCD-aware 2D chunking (xcd = blockIdx%8 round-robin assumption).
    const int xcd = blockIdx.x & 7, wi = blockIdx.x >> 3;
    int bm, bn;
    if constexpr (NBN == 32) {           // 8 x 32 grid (MODE 0)
        bm = (xcd >> 2) * 4 + (wi >> 3);
        bn = (xcd & 3) * 8 + (wi & 7);
    } else {                             // 16 x 16 grid (MODE 1)
        bm = (xcd & 3) * 4 + (wi >> 3);
        bn = (xcd >> 2) * 8 + (wi & 7);
    }

    // staging: thread tid fills phys bytes [line*8192 + tid*16, +16) of a region
    // = logical row line*64 + tid/8, col ((tid&7)^((tid>>3)&7))*16 (swizzled src)
    const int srow = tid >> 3;
    const int scol = ((tid & 7) ^ ((tid >> 3) & 7)) << 4;
    const char* spA[NLA];
    const char* spB[NLB];
#pragma unroll
    for (int L = 0; L < NLA; ++L)
        spA[L] = (const char*)(A + (size_t)(bm * BM + L * 64 + srow) * 4096) + scol;
#pragma unroll
    for (int L = 0; L < NLB; ++L)
        spB[L] = (const char*)(BT + (size_t)(bn * BN + L * 64 + srow) * 4096) + scol;

#define STG_A(L, tt, b) GLOAD_LDS16(spA[L] + (size_t)(tt) * 128, &lds[b][(L) * 4096 + w * 512])
#define STG_B(L, tt, b) GLOAD_LDS16(spB[L] + (size_t)(tt) * 128, &lds[b][BM * 64 + (L) * 4096 + w * 512])

    // prologue: stage tiles 0 and 1, wait for tile 0 only (NL of tile 1 in flight)
#pragma unroll
    for (int L = 0; L < NLA; ++L) STG_A(L, 0, 0);
#pragma unroll
    for (int L = 0; L < NLB; ++L) STG_B(L, 0, 0);
#pragma unroll
    for (int L = 0; L < NLA; ++L) STG_A(L, 1, 1);
#pragma unroll
    for (int L = 0; L < NLB; ++L) STG_B(L, 1, 1);
    if constexpr (NL == 7) asm volatile("s_waitcnt vmcnt(7)" ::: "memory");
    else                   asm volatile("s_waitcnt vmcnt(6)" ::: "memory");
    asm volatile("s_barrier" ::: "memory");

    // read-side swizzle: frag row = 16*frag + l15 -> row&7 == l15&7
    const int c0x = (q4 * 16) ^ ((l15 & 7) << 4);
    const int c1x = c0x ^ 64;

    f32x4 acc[WM][WN] = {};
    bf8 breg[WN][2];

#pragma unroll 1
    for (int t = 0; t < NT; ++t) {
        const int cur = t & 1;
        const char* ldsA = (const char*)&lds[cur][0];
        const char* ldsB = ldsA + BM * 128;
#pragma unroll
        for (int p = 0; p < 4; ++p) {
            // stage tile t+2 B-lines into buf[cur] (B read only in p0 -> dead)
            if (p == 1 && t < NT - 2) {
#pragma unroll
                for (int L = 0; L < NLB; ++L) STG_B(L, t + 2, cur);
            }
            bf8 areg[MP][2];
#pragma unroll
            for (int j = 0; j < MP; ++j) {
                const char* rp = ldsA + (wm * (WM * 16) + (p * MP + j) * 16 + l15) * 128;
                areg[j][0] = *(const bf8*)(rp + c0x);
                areg[j][1] = *(const bf8*)(rp + c1x);
            }
            if (p == 0) {
#pragma unroll
                for (int nf = 0; nf < WN; ++nf) {
                    const char* rp = ldsB + (wn * (WN * 16) + nf * 16 + l15) * 128;
                    breg[nf][0] = *(const bf8*)(rp + c0x);
                    breg[nf][1] = *(const bf8*)(rp + c1x);
                }
            }
            asm volatile("s_barrier" ::: "memory");
            asm volatile("s_waitcnt lgkmcnt(0)" ::: "memory");
            __builtin_amdgcn_s_setprio(1);
#pragma unroll
            for (int j = 0; j < MP; ++j)
#pragma unroll
                for (int nf = 0; nf < WN; ++nf)
#pragma unroll
                    for (int ks = 0; ks < 2; ++ks)
                        acc[p * MP + j][nf] = __builtin_amdgcn_mfma_f32_16x16x32_bf16(
                            areg[j][ks], breg[nf][ks], acc[p * MP + j][nf], 0, 0, 0);
            __builtin_amdgcn_s_setprio(0);
            asm volatile("s_barrier" ::: "memory");
        }
        // boundary: stage all A lines of t+2 (live through p3), then counted
        // vmcnt -- tile t+1 fully landed, t+2's NL loads stay in flight.
        if (t < NT - 2) {
#pragma unroll
            for (int L = 0; L < NLA; ++L) STG_A(L, t + 2, cur);
            if constexpr (NL == 7) asm volatile("s_waitcnt vmcnt(7)" ::: "memory");
            else                   asm volatile("s_waitcnt vmcnt(6)" ::: "memory");
        } else if (t == NT - 2) {
            asm volatile("s_waitcnt vmcnt(0)" ::: "memory");
        }
        asm volatile("s_barrier" ::: "memory");
    }
#undef STG_A
#undef STG_B

    const int rowb = bm * BM + wm * (WM * 16);
    const int colb = bn * BN + wn * (WN * 16);
#pragma unroll
    for (int mf = 0; mf < WM; ++mf)
#pragma unroll
        for (int nf = 0; nf < WN; ++nf)
#pragma unroll
            for (int r = 0; r < 4; ++r) {
                const int row = rowb + mf * 16 + q4 * 4 + r;
                const int col = colb + nf * 16 + l15;
                if constexpr (MODE == 0)
                    Cbf[(size_t)row * CSTR + col] = f2bf(acc[mf][nf][r]);
                else
                    Cf[(size_t)row * CSTR + col] = acc[mf][nf][r];
            }
}

// ---------------- flash attention ----------------
// grid: 512 = 16 q-tiles * 32 heads. block 256 = 4 waves, each wave owns 32 Q rows.
// No running max (scores bounded), unnormalized p=exp2(s*cs), per-lane row-sum,
// one shuffle-reduce + normalize at the end.
// K/V LDS layouts restructured into GEMM-shaped [*][64 bf16] sub-tiles carrying
// the GEMM-verified ZERO-CONFLICT swizzle (old 64-B-row layout put kf/vf reads
// at 8 lanes/slot = 8-way conflict, ~2.9x LDS cost).
//   K: [2 d-half][64 rows][64] at sm[0..8192); V: [128 d][64 seq] at sm[8192..16384)
//   store: logical (r, c16B) at phys c ^ (r&7)  (pre-swizzled gload source)
//   read:  byte col = ((q4 ^ (l15&7))<<4) ^ (kslice<<6), row stride 128 B
#define PSTR 72   // P row stride in shorts: 64 cols + 8 pad (2-way alias = free)
__global__ __launch_bounds__(256) void attn_kernel(const u16* __restrict__ xqkv,
                                                   const u16* __restrict__ vt,
                                                   u16* __restrict__ aw) {
    __shared__ __align__(16) u16 sm[16384 + 128 * PSTR];
    const int tid = threadIdx.x, w = tid >> 6, l = tid & 63, l15 = l & 15, q4 = l >> 4;
    const int qh = blockIdx.x & 31;
    const int qslot = blockIdx.x >> 5;
    // complementary pairing: blocks b and b+256 get qt summing to 15 (tail balance)
    const int qt = (qslot < 8) ? qslot : 23 - qslot;
    const int kh = qh >> 2;

    { // stage Q tile: [ks=w][row 128][32], async (one-time; layout legacy)
        const u16* gq = xqkv + (size_t)(qt * 128 + (l >> 2)) * DQKV + qh * HD + w * 32 + (l & 3) * 8;
#pragma unroll
        for (int i = 0; i < 8; ++i)
            GLOAD_LDS16(gq + (size_t)i * 16 * DQKV, &sm[w * 4096 + i * 512]);
    }
    __syncthreads();
    bf8 qf[4][2];
#pragma unroll
    for (int ks = 0; ks < 4; ++ks)
#pragma unroll
        for (int mt = 0; mt < 2; ++mt)
            qf[ks][mt] = *(const bf8*)&sm[ks * 4096 + (w * 32 + mt * 16 + l15) * 32 + q4 * 8];
    __syncthreads();

    f32x4 O[2][8] = {};
    float plrow[2][4] = {};   // per-lane unnormalized row-sum partials

    u16* ldsK = sm;           // [2][64][64] shorts
    u16* ldsV = sm + 8192;    // [128][64] shorts
    u16* ldsP = sm + 16384;
    const int nkt = 2 * qt + 2;
    const float cs = 0.12751744f; // (1/sqrt(128)) * log2(e)

    // staging source swizzle (GEMM-verified): lane l covers phys row-in-group
    // l>>3, slot l&7 -> loads logical col ((l&7)^(l>>3))*8 elems
    const int sr8 = l >> 3;
    const int sc8 = (l & 7) ^ sr8;
    // K: wave w stages d-half (w&1), seq rows (w>>1)*32..+32
    const u16* gk_base = xqkv + (size_t)((w >> 1) * 32 + sr8) * DQKV + (32 + kh) * HD + (w & 1) * 64 + sc8 * 8;
    u16* ldsK_dst = ldsK + (w & 1) * 4096 + (w >> 1) * 2048;
    // V: wave w stages d-rows w*32..+32 (cols = seq kt*64..+64)
    const u16* gv_base = vt + ((size_t)kh * HD + w * 32 + sr8) * SEQ + sc8 * 8;
    u16* ldsV_dst = ldsV + w * 2048;

    const int cswz = (q4 ^ (l15 & 7)) << 4;   // read-side swizzled byte col
    const char* Kb = (const char*)ldsK;
    const char* Vb = (const char*)ldsV;

    for (int kt = 0; kt < nkt; ++kt) {
        { // stage K tile [64 seq][128 d] as 2 GEMM-shaped sub-tiles
            const u16* gk = gk_base + (size_t)(kt * 64) * DQKV;
#pragma unroll
            for (int i = 0; i < 4; ++i)
                GLOAD_LDS16(gk + (size_t)i * 8 * DQKV, ldsK_dst + i * 512);
        }
        { // stage V^T tile [128 d][64 seq]
            const u16* gv = gv_base + kt * 64;
#pragma unroll
            for (int i = 0; i < 4; ++i)
                GLOAD_LDS16(gv + (size_t)i * 8 * SEQ, ldsV_dst + i * 512);
        }
        __syncthreads();   // drains vmcnt

        // S = Q K^T
        f32x4 S[2][4] = {};
#pragma unroll
        for (int ks = 0; ks < 4; ++ks) {
            bf8 kf[4];
#pragma unroll
            for (int nt = 0; nt < 4; ++nt)
                kf[nt] = *(const bf8*)(Kb + (ks >> 1) * 8192 + (nt * 16 + l15) * 128
                                       + (cswz ^ ((ks & 1) << 6)));
#pragma unroll
            for (int mt = 0; mt < 2; ++mt)
#pragma unroll
                for (int nt = 0; nt < 4; ++nt)
                    S[mt][nt] = __builtin_amdgcn_mfma_f32_16x16x32_bf16(qf[ks][mt], kf[nt], S[mt][nt], 0, 0, 0);
        }

        const bool domask = (kt >= 2 * qt);
#pragma unroll
        for (int mt = 0; mt < 2; ++mt)
#pragma unroll
            for (int r = 0; r < 4; ++r) {
                const int row = qt * 128 + w * 32 + mt * 16 + q4 * 4 + r;
#pragma unroll
                for (int nt = 0; nt < 4; ++nt) {
                    float t = S[mt][nt][r] * cs;
                    if (domask && (kt * 64 + nt * 16 + l15 > row)) t = -1e30f;
                    float p = exp2f(t);
                    plrow[mt][r] += p;
                    ldsP[(w * 32 + mt * 16 + q4 * 4 + r) * PSTR + nt * 16 + l15] = f2bf(p);
                }
            }

        // O += P V   (P rows are wave-private: no barrier needed)
#pragma unroll
        for (int pk = 0; pk < 2; ++pk) {
            bf8 pf[2], vf[8];
#pragma unroll
            for (int mt = 0; mt < 2; ++mt)
                pf[mt] = *(const bf8*)&ldsP[(w * 32 + mt * 16 + l15) * PSTR + pk * 32 + q4 * 8];
#pragma unroll
            for (int nt = 0; nt < 8; ++nt)
                vf[nt] = *(const bf8*)(Vb + (nt * 16 + l15) * 128 + (cswz ^ (pk << 6)));
#pragma unroll
            for (int mt = 0; mt < 2; ++mt)
#pragma unroll
                for (int nt = 0; nt < 8; ++nt)
                    O[mt][nt] = __builtin_amdgcn_mfma_f32_16x16x32_bf16(pf[mt], vf[nt], O[mt][nt], 0, 0, 0);
        }
        __syncthreads();   // all waves done reading K/V/P before next stage
    }

#pragma unroll
    for (int mt = 0; mt < 2; ++mt)
#pragma unroll
        for (int r = 0; r < 4; ++r) {
            float ls = plrow[mt][r];   // row-sum lives across the 16 lanes of this q4 group
#pragma unroll
            for (int off = 1; off <= 8; off <<= 1)
                ls += __shfl_xor(ls, off, 64);
            const float linv = 1.0f / ls;
            const int row = qt * 128 + w * 32 + mt * 16 + q4 * 4 + r;
#pragma unroll
            for (int nt = 0; nt < 8; ++nt)
                aw[(size_t)row * 4096 + qh * HD + nt * 16 + l15] = f2bf(O[mt][nt][r] * linv);
        }
}

// ---------------- launch ----------------

extern "C" void kernel_launch(void* const* d_in, const int* in_sizes, int n_in,
                              void* d_out, int out_size, void* d_ws, size_t ws_size,
                              hipStream_t stream) {
    const float* hs = (const float*)d_in[0];
    const float* wqkv = (const float*)d_in[1];
    const float* wo = (const float*)d_in[2];
    float* out = (float*)d_out;

    char* ws = (char*)d_ws;
    const size_t oHbf = 0;
    const size_t oWqkvT = oHbf + (size_t)SEQ * HIDDEN * 2;          // 16.78 MB
    const size_t oWoT = oWqkvT + (size_t)DQKV * HIDDEN * 2;         // +50.33 MB
    const size_t oXQKV = oWoT + (size_t)HIDDEN * HIDDEN * 2;        // +33.55 MB
    const size_t oVT = oXQKV + (size_t)SEQ * DQKV * 2;              // +25.17 MB
    const size_t oAW = oVT + (size_t)8 * HD * SEQ * 2;              // +4.19 MB
    const size_t total = oAW + (size_t)SEQ * HIDDEN * 2;            // +16.78 MB = 146.8 MB
    if (ws_size < total) return;

    u16* Hbf = (u16*)(ws + oHbf);
    u16* WqkvT = (u16*)(ws + oWqkvT);
    u16* WoT = (u16*)(ws + oWoT);
    u16* XQKV = (u16*)(ws + oXQKV);
    u16* VT = (u16*)(ws + oVT);
    u16* AW = (u16*)(ws + oAW);

    convert_bf16_kernel<<<(SEQ * HIDDEN) / 1024, 256, 0, stream>>>(hs, Hbf);
    transpose_w_kernel<<<(HIDDEN / 64) * (DQKV / 64), 256, 0, stream>>>(wqkv, WqkvT, HIDDEN, DQKV);
    transpose_w_kernel<<<(HIDDEN / 64) * (HIDDEN / 64), 256, 0, stream>>>(wo, WoT, HIDDEN, HIDDEN);
    gemm8p_kernel<256, 192, 0><<<256, 512, 0, stream>>>(Hbf, WqkvT, XQKV, nullptr);  // 8x32 grid
    rope_kernel<<<SEQ * 10, 256, 0, stream>>>(XQKV);
    transpose_v_kernel<<<8 * 64, 256, 0, stream>>>(XQKV, VT);
    attn_kernel<<<512, 256, 0, stream>>>(XQKV, VT, AW);
    gemm8p_kernel<128, 256, 1><<<256, 512, 0, stream>>>(AW, WoT, nullptr, out);      // 16x16 grid
}